// Round 1
// baseline (613.600 us; speedup 1.0000x reference)
//
#include <hip/hip_runtime.h>

#define E 16
#define HID 32
#define NSTEP 10
#define TAU 0.5f
#define SIGMA 0.5f
#define RES 0.5f

__device__ __forceinline__ float fast_tanh(float v) {
    // tanh(v) = 1 - 2/(exp(2v)+1); inf-safe at both ends
    float e = __expf(2.0f * v);
    return 1.0f - __fdividef(2.0f, e + 1.0f);
}

__global__ __launch_bounds__(256, 2) void pdhg_kernel(
    const float* __restrict__ xg,  const float* __restrict__ Gg,  const float* __restrict__ hg,
    const float* __restrict__ W1,  const float* __restrict__ b1,
    const float* __restrict__ W2,  const float* __restrict__ b2,
    const float* __restrict__ Wmu, const float* __restrict__ bmu,
    const float* __restrict__ Wy,  const float* __restrict__ by,
    const float* __restrict__ Wp1, const float* __restrict__ bp1,
    const float* __restrict__ Wp2, const float* __restrict__ bp2,
    float* __restrict__ out, int npts)
{
    const int t = blockIdx.x * blockDim.x + threadIdx.x;
    const int p0 = 2 * t;
    if (p0 >= npts) return;

    // two points per thread: A = (xv.x, xv.y), B = (xv.z, xv.w)
    const float4 xv = reinterpret_cast<const float4*>(xg)[t];
    const float x0a = xv.x, x1a = xv.y;
    const float x0b = xv.z, x1b = xv.w;

    // ---------------- encoder layer 1: relu(x @ W1 + b1) ----------------
    float fa[HID], fb[HID];
    #pragma unroll
    for (int j = 0; j < HID; ++j) {
        const float w0 = W1[j], w1 = W1[HID + j], bb = b1[j];
        fa[j] = fmaxf(fmaf(x0a, w0, fmaf(x1a, w1, bb)), 0.0f);
        fb[j] = fmaxf(fmaf(x0b, w0, fmaf(x1b, w1, bb)), 0.0f);
    }

    // ---------------- encoder layer 2: relu(f @ W2 + b2) ----------------
    float ga[HID], gb[HID];
    #pragma unroll
    for (int j = 0; j < HID; ++j) { const float bb = b2[j]; ga[j] = bb; gb[j] = bb; }
    #pragma unroll
    for (int i = 0; i < HID; ++i) {
        const float va = fa[i], vb = fb[i];
        #pragma unroll
        for (int j = 0; j < HID; ++j) {
            const float w = W2[i * HID + j];
            ga[j] = fmaf(va, w, ga[j]);
            gb[j] = fmaf(vb, w, gb[j]);
        }
    }
    #pragma unroll
    for (int j = 0; j < HID; ++j) { ga[j] = fmaxf(ga[j], 0.0f); gb[j] = fmaxf(gb[j], 0.0f); }

    // ---------------- mu = relu(g @ Wmu + bmu) ----------------
    float mua[E], mub[E];
    #pragma unroll
    for (int e = 0; e < E; ++e) { const float bb = bmu[e]; mua[e] = bb; mub[e] = bb; }
    #pragma unroll
    for (int i = 0; i < HID; ++i) {
        const float va = ga[i], vb = gb[i];
        #pragma unroll
        for (int e = 0; e < E; ++e) {
            const float w = Wmu[i * E + e];
            mua[e] = fmaf(va, w, mua[e]);
            mub[e] = fmaf(vb, w, mub[e]);
        }
    }
    #pragma unroll
    for (int e = 0; e < E; ++e) { mua[e] = fmaxf(mua[e], 0.0f); mub[e] = fmaxf(mub[e], 0.0f); }

    // ---------------- y = tanh(g @ Wy + by) ----------------
    float ya0 = by[0], ya1 = by[1], yb0 = by[0], yb1 = by[1];
    #pragma unroll
    for (int i = 0; i < HID; ++i) {
        const float w0 = Wy[i * 2], w1 = Wy[i * 2 + 1];
        ya0 = fmaf(ga[i], w0, ya0); ya1 = fmaf(ga[i], w1, ya1);
        yb0 = fmaf(gb[i], w0, yb0); yb1 = fmaf(gb[i], w1, yb1);
    }
    ya0 = fast_tanh(ya0); ya1 = fast_tanh(ya1);
    yb0 = fast_tanh(yb0); yb1 = fast_tanh(yb1);

    // ---------------- a_row = x @ G^T - h^T ----------------
    float aa[E], ab[E];
    #pragma unroll
    for (int e = 0; e < E; ++e) {
        const float g0 = Gg[e * 2], g1 = Gg[e * 2 + 1], hh = hg[e];
        aa[e] = fmaf(x0a, g0, fmaf(x1a, g1, -hh));
        ab[e] = fmaf(x0b, g0, fmaf(x1b, g1, -hh));
    }

    // ---------------- PDHG steps ----------------
    #pragma unroll 1
    for (int s = 0; s < NSTEP; ++s) {
        // y += SIGMA * (mu @ G); project to unit ball
        float va0 = 0.f, va1 = 0.f, vb0 = 0.f, vb1 = 0.f;
        #pragma unroll
        for (int e = 0; e < E; ++e) {
            const float g0 = Gg[e * 2], g1 = Gg[e * 2 + 1];
            va0 = fmaf(mua[e], g0, va0); va1 = fmaf(mua[e], g1, va1);
            vb0 = fmaf(mub[e], g0, vb0); vb1 = fmaf(mub[e], g1, vb1);
        }
        ya0 = fmaf(SIGMA, va0, ya0); ya1 = fmaf(SIGMA, va1, ya1);
        yb0 = fmaf(SIGMA, vb0, yb0); yb1 = fmaf(SIGMA, vb1, yb1);
        {
            const float na = sqrtf(fmaf(ya0, ya0, ya1 * ya1));
            const float sa = __fdividef(1.0f, fmaxf(na, 1.0f));
            ya0 *= sa; ya1 *= sa;
            const float nb = sqrtf(fmaf(yb0, yb0, yb1 * yb1));
            const float sb = __fdividef(1.0f, fmaxf(nb, 1.0f));
            yb0 *= sb; yb1 *= sb;
        }

        // mu += TAU * (a - y @ G^T), then z = mu @ G
        float za0 = 0.f, za1 = 0.f, zb0 = 0.f, zb1 = 0.f;
        #pragma unroll
        for (int e = 0; e < E; ++e) {
            const float g0 = Gg[e * 2], g1 = Gg[e * 2 + 1];
            const float da = fmaf(ya0, g0, ya1 * g1);
            const float db = fmaf(yb0, g0, yb1 * g1);
            mua[e] = fmaf(TAU, aa[e] - da, mua[e]);
            mub[e] = fmaf(TAU, ab[e] - db, mub[e]);
            za0 = fmaf(mua[e], g0, za0); za1 = fmaf(mua[e], g1, za1);
            zb0 = fmaf(mub[e], g0, zb0); zb1 = fmaf(mub[e], g1, zb1);
        }

        // prox head hidden: relu(z @ Wp1 + bp1)
        float ha[HID], hb[HID];
        #pragma unroll
        for (int k = 0; k < HID; ++k) {
            const float w0 = Wp1[k], w1 = Wp1[HID + k], bb = bp1[k];
            ha[k] = fmaxf(fmaf(za0, w0, fmaf(za1, w1, bb)), 0.0f);
            hb[k] = fmaxf(fmaf(zb0, w0, fmaf(zb1, w1, bb)), 0.0f);
        }
        // delta = h @ Wp2 + bp2
        float da_[E], db_[E];
        #pragma unroll
        for (int e = 0; e < E; ++e) { const float bb = bp2[e]; da_[e] = bb; db_[e] = bb; }
        #pragma unroll
        for (int k = 0; k < HID; ++k) {
            const float va = ha[k], vb = hb[k];
            #pragma unroll
            for (int e = 0; e < E; ++e) {
                const float w = Wp2[k * E + e];
                da_[e] = fmaf(va, w, da_[e]);
                db_[e] = fmaf(vb, w, db_[e]);
            }
        }

        // mu = project_mu(mu + RES * delta)
        float pa0 = 0.f, pa1 = 0.f, pb0 = 0.f, pb1 = 0.f;
        #pragma unroll
        for (int e = 0; e < E; ++e) {
            const float g0 = Gg[e * 2], g1 = Gg[e * 2 + 1];
            mua[e] = fmaxf(fmaf(RES, da_[e], mua[e]), 0.0f);
            mub[e] = fmaxf(fmaf(RES, db_[e], mub[e]), 0.0f);
            pa0 = fmaf(mua[e], g0, pa0); pa1 = fmaf(mua[e], g1, pa1);
            pb0 = fmaf(mub[e], g0, pb0); pb1 = fmaf(mub[e], g1, pb1);
        }
        {
            const float na = sqrtf(fmaf(pa0, pa0, pa1 * pa1));
            const float sa = __fdividef(1.0f, fmaxf(na, 1.0f));
            const float nb = sqrtf(fmaf(pb0, pb0, pb1 * pb1));
            const float sb = __fdividef(1.0f, fmaxf(nb, 1.0f));
            #pragma unroll
            for (int e = 0; e < E; ++e) { mua[e] *= sa; mub[e] *= sb; }
        }
    }

    // ---------------- final project_mu (idempotent but match reference) ----------------
    {
        float pa0 = 0.f, pa1 = 0.f, pb0 = 0.f, pb1 = 0.f;
        #pragma unroll
        for (int e = 0; e < E; ++e) {
            const float g0 = Gg[e * 2], g1 = Gg[e * 2 + 1];
            mua[e] = fmaxf(mua[e], 0.0f);
            mub[e] = fmaxf(mub[e], 0.0f);
            pa0 = fmaf(mua[e], g0, pa0); pa1 = fmaf(mua[e], g1, pa1);
            pb0 = fmaf(mub[e], g0, pb0); pb1 = fmaf(mub[e], g1, pb1);
        }
        const float na = sqrtf(fmaf(pa0, pa0, pa1 * pa1));
        const float sa = __fdividef(1.0f, fmaxf(na, 1.0f));
        const float nb = sqrtf(fmaf(pb0, pb0, pb1 * pb1));
        const float sb = __fdividef(1.0f, fmaxf(nb, 1.0f));
        #pragma unroll
        for (int e = 0; e < E; ++e) { mua[e] *= sa; mub[e] *= sb; }
    }

    // ---------------- store [2 points x 16] = 32 contiguous floats ----------------
    float4* outv = reinterpret_cast<float4*>(out + (size_t)p0 * E);
    outv[0] = make_float4(mua[0],  mua[1],  mua[2],  mua[3]);
    outv[1] = make_float4(mua[4],  mua[5],  mua[6],  mua[7]);
    outv[2] = make_float4(mua[8],  mua[9],  mua[10], mua[11]);
    outv[3] = make_float4(mua[12], mua[13], mua[14], mua[15]);
    outv[4] = make_float4(mub[0],  mub[1],  mub[2],  mub[3]);
    outv[5] = make_float4(mub[4],  mub[5],  mub[6],  mub[7]);
    outv[6] = make_float4(mub[8],  mub[9],  mub[10], mub[11]);
    outv[7] = make_float4(mub[12], mub[13], mub[14], mub[15]);
}

extern "C" void kernel_launch(void* const* d_in, const int* in_sizes, int n_in,
                              void* d_out, int out_size, void* d_ws, size_t ws_size,
                              hipStream_t stream) {
    const float* x   = (const float*)d_in[0];
    const float* G   = (const float*)d_in[1];
    const float* h   = (const float*)d_in[2];
    const float* W1  = (const float*)d_in[3];
    const float* b1  = (const float*)d_in[4];
    const float* W2  = (const float*)d_in[5];
    const float* b2  = (const float*)d_in[6];
    const float* Wmu = (const float*)d_in[7];
    const float* bmu = (const float*)d_in[8];
    const float* Wy  = (const float*)d_in[9];
    const float* by  = (const float*)d_in[10];
    const float* Wp1 = (const float*)d_in[11];
    const float* bp1 = (const float*)d_in[12];
    const float* Wp2 = (const float*)d_in[13];
    const float* bp2 = (const float*)d_in[14];

    const int npts = in_sizes[0] / 2;        // x is [N,2]
    const int nthreads = (npts + 1) / 2;     // 2 points per thread
    const int block = 256;
    const int grid = (nthreads + block - 1) / block;

    pdhg_kernel<<<grid, block, 0, stream>>>(x, G, h, W1, b1, W2, b2, Wmu, bmu,
                                            Wy, by, Wp1, bp1, Wp2, bp2,
                                            (float*)d_out, npts);
}